// Round 24
// baseline (106.076 us; speedup 1.0000x reference)
//
#include <hip/hip_runtime.h>
#include <hip/hip_bf16.h>
#include <hip/hip_fp16.h>
#include <cstdint>

// B=8, S=2048, D=256 fused attention block, fp32 in/out.
// Round 24: attn K double-buffered (LDS 129KB, still 1 block/CU — occupancy
// is register-bound at 2 waves/SIMD anyway). All K+V staging for tile t+1
// issues at the TOP of tile t into the ^1 buffers: both mid-tile raw
// barriers deleted (no WAR on Ks), and the end-of-tile __syncthreads drain
// waits on loads a full tile old (~free). Barriers/tile 3 -> 1.
// Rest byte-identical to round 23 (93.1us: fused QKV, fused combine+out+LN).

#define RROWS 16384
#define DD 256
#define SEQ 2048
#define NB 8
#define QBLK 256
#define KVBLK 64
#define NTILES (SEQ / KVBLK)

typedef _Float16 f16x8 __attribute__((ext_vector_type(8)));
typedef _Float16 f16x4 __attribute__((ext_vector_type(4)));
typedef float f32x4 __attribute__((ext_vector_type(4)));
typedef float f32x16 __attribute__((ext_vector_type(16)));

// ---------------------------------------------------------------------------
// weight cast (q,k,v,d -> Wh[4][65536])
// ---------------------------------------------------------------------------
__global__ __launch_bounds__(256) void cast_w_kernel(
    const float* __restrict__ w0, const float* __restrict__ w1,
    const float* __restrict__ w2, const float* __restrict__ w3,
    _Float16* __restrict__ dst)
{
  const float* srcs[4] = {w0, w1, w2, w3};
  const float* src = srcs[blockIdx.y];
  _Float16* d = dst + (size_t)blockIdx.y * 65536;
  const size_t i = ((size_t)blockIdx.x * 256 + threadIdx.x) * 8;
  float4 a = *(const float4*)&src[i];
  float4 b = *(const float4*)&src[i + 4];
  f16x8 h = { (_Float16)a.x, (_Float16)a.y, (_Float16)a.z, (_Float16)a.w,
              (_Float16)b.x, (_Float16)b.y, (_Float16)b.z, (_Float16)b.w };
  *(f16x8*)&d[i] = h;
}

// ---------------------------------------------------------------------------
// Fused QKV projection: X fp32 -> {Qh (row-major), Kh (swizzled ^r&31),
// VtG (tiled [b][s/64][256 d][64 s], granule-swizzled ^d&7)}.
// ---------------------------------------------------------------------------
__global__ __launch_bounds__(256) void gemm_qkv_kernel(
    const float* __restrict__ X, const _Float16* __restrict__ Wh,
    const float* __restrict__ bq, const float* __restrict__ bk,
    const float* __restrict__ bv,
    _Float16* __restrict__ Qh, _Float16* __restrict__ Kh,
    _Float16* __restrict__ VtG)
{
  __shared__ _Float16 smem[128 * 264];
  const int t     = threadIdx.x;
  const int lane  = t & 63;
  const int w     = t >> 6;
  const int rows0 = blockIdx.x * 64;
  const int col0  = blockIdx.y * 128;
  const int lr = lane & 15;
  const int lg = lane >> 4;

  f16x8 qf[8];
  {
    const float* xrow = X + (size_t)(rows0 + w * 16 + lr) * DD;
#pragma unroll
    for (int ks = 0; ks < 8; ++ks) {
      float4 a = *(const float4*)&xrow[ks * 32 + lg * 8];
      float4 b = *(const float4*)&xrow[ks * 32 + lg * 8 + 4];
      qf[ks] = (f16x8){ (_Float16)a.x, (_Float16)a.y, (_Float16)a.z, (_Float16)a.w,
                        (_Float16)b.x, (_Float16)b.y, (_Float16)b.z, (_Float16)b.w };
    }
  }

  for (int o = 0; o < 3; ++o) {
    const _Float16* W = Wh + (size_t)o * 65536;
    __syncthreads();
#pragma unroll
    for (int i = 0; i < 16; ++i) {
      int ch = i * 256 + t;
      int er = ch >> 5, kc = (ch & 31) * 8;
      *(f16x8*)&smem[er * 264 + kc] = *(const f16x8*)&W[(size_t)(col0 + er) * DD + kc];
    }
    __syncthreads();

    f32x4 acc[8];
#pragma unroll
    for (int i = 0; i < 8; ++i) acc[i] = (f32x4){0.f, 0.f, 0.f, 0.f};
#pragma unroll
    for (int ct = 0; ct < 8; ++ct)
#pragma unroll
      for (int ks = 0; ks < 8; ++ks) {
        f16x8 wf = *(const f16x8*)&smem[(ct * 16 + lr) * 264 + ks * 32 + lg * 8];
        acc[ct] = __builtin_amdgcn_mfma_f32_16x16x32_f16(qf[ks], wf, acc[ct], 0, 0, 0);
      }

    const float* bp = (o == 0) ? bq : (o == 1) ? bk : bv;
    float bf[8];
#pragma unroll
    for (int ct = 0; ct < 8; ++ct) bf[ct] = bp[col0 + ct * 16 + lr];

    if (o == 0) {
#pragma unroll
      for (int ct = 0; ct < 8; ++ct)
#pragma unroll
        for (int j = 0; j < 4; ++j) {
          int r = rows0 + w * 16 + lg * 4 + j;
          Qh[(size_t)r * DD + col0 + ct * 16 + lr] = (_Float16)(acc[ct][j] + bf[ct]);
        }
    } else if (o == 1) {
#pragma unroll
      for (int ct = 0; ct < 8; ++ct)
#pragma unroll
        for (int j = 0; j < 4; ++j) {
          int r = rows0 + w * 16 + lg * 4 + j;
          int c = col0 + ct * 16 + lr;
          Kh[(size_t)r * DD + (((c >> 3) ^ (r & 31)) << 3) + (c & 7)] =
              (_Float16)(acc[ct][j] + bf[ct]);
        }
    } else {
      __syncthreads();
      _Float16* T = smem;   // [128 e][72 s]
#pragma unroll
      for (int ct = 0; ct < 8; ++ct)
#pragma unroll
        for (int j = 0; j < 4; ++j)
          T[(ct * 16 + lr) * 72 + (w * 16 + lg * 4 + j)] = (_Float16)(acc[ct][j] + bf[ct]);
      __syncthreads();
      const int bIdx = rows0 >> 11;
      const int tIdx = (rows0 & (SEQ - 1)) >> 6;
      _Float16* base = VtG + (((size_t)bIdx * NTILES + tIdx) * DD + col0) * KVBLK;
#pragma unroll
      for (int p = 0; p < 4; ++p) {
        int ch = p * 256 + t;
        int e = ch >> 3, sc = (ch & 7) * 8;
        int g = (sc >> 3) ^ (e & 7);
        *(f16x8*)&base[(size_t)e * KVBLK + (g << 3)] = *(const f16x8*)&T[e * 72 + sc];
      }
    }
  }
}

// ---------------------------------------------------------------------------
// (combine + out-projection + residual + LayerNorm) fused.
// ---------------------------------------------------------------------------
__global__ __launch_bounds__(256) void gemm_outln_kernel(
    const _Float16* __restrict__ Op, const float* __restrict__ Mp,
    const float* __restrict__ Lp, int nsplit,
    const _Float16* __restrict__ W, const float* __restrict__ bias,
    const float* __restrict__ res, const float* __restrict__ gv,
    const float* __restrict__ bv, float* __restrict__ out)
{
  __shared__ _Float16 smem[128 * 264];
  const int t     = threadIdx.x;
  const int lane  = t & 63;
  const int w     = t >> 6;
  const int rows0 = blockIdx.x * 64;
  const int lr = lane & 15;
  const int lg = lane >> 4;
  const size_t R = (size_t)rows0 + w * 16 + lr;     // this thread's ctx row

  // combine weights for row R
  float wgt[4];
  {
    float ms = -1e30f;
    for (int s = 0; s < nsplit; ++s) ms = fmaxf(ms, Mp[(size_t)s * RROWS + R]);
    float ctot = 0.f;
    for (int s = 0; s < nsplit; ++s) {
      float c = __expf(Mp[(size_t)s * RROWS + R] - ms) * Lp[(size_t)s * RROWS + R];
      wgt[s] = c; ctot += c;
    }
    float inv = 1.0f / ctot;
    for (int s = 0; s < nsplit; ++s) wgt[s] *= inv;
  }

  // A fragments = sum_s wgt[s] * Op_s[row R]
  f16x8 qf[8];
#pragma unroll
  for (int ks = 0; ks < 8; ++ks) {
    float cf[8] = {0.f, 0.f, 0.f, 0.f, 0.f, 0.f, 0.f, 0.f};
    for (int s = 0; s < nsplit; ++s) {
      f16x8 o = *(const f16x8*)&Op[((size_t)s * RROWS + R) * DD + ks * 32 + lg * 8];
#pragma unroll
      for (int e = 0; e < 8; ++e) cf[e] += wgt[s] * (float)o[e];
    }
    qf[ks] = (f16x8){ (_Float16)cf[0], (_Float16)cf[1], (_Float16)cf[2], (_Float16)cf[3],
                      (_Float16)cf[4], (_Float16)cf[5], (_Float16)cf[6], (_Float16)cf[7] };
  }

  f32x4 acc[16];
#pragma unroll
  for (int i = 0; i < 16; ++i) acc[i] = (f32x4){0.f, 0.f, 0.f, 0.f};

  for (int half = 0; half < 2; ++half) {
    const int col0 = half * 128;
    __syncthreads();
#pragma unroll
    for (int i = 0; i < 16; ++i) {
      int ch = i * 256 + t;
      int er = ch >> 5, kc = (ch & 31) * 8;
      *(f16x8*)&smem[er * 264 + kc] = *(const f16x8*)&W[(size_t)(col0 + er) * DD + kc];
    }
    __syncthreads();
#pragma unroll
    for (int ct = 0; ct < 8; ++ct)
#pragma unroll
      for (int ks = 0; ks < 8; ++ks) {
        f16x8 wf = *(const f16x8*)&smem[(ct * 16 + lr) * 264 + ks * 32 + lg * 8];
        acc[half * 8 + ct] =
            __builtin_amdgcn_mfma_f32_16x16x32_f16(qf[ks], wf, acc[half * 8 + ct], 0, 0, 0);
      }
  }

  // h = acc + bias + x
#pragma unroll
  for (int ct = 0; ct < 16; ++ct) {
    const int c = ct * 16 + lr;
    const float bf = bias[c];
#pragma unroll
    for (int j = 0; j < 4; ++j) {
      const int r = rows0 + w * 16 + lg * 4 + j;
      acc[ct][j] += bf + res[(size_t)r * DD + c];
    }
  }

  // LN over 256 cols (16 lr-lanes x 16 cts per lg group)
  float sm[4] = {0.f, 0.f, 0.f, 0.f};
#pragma unroll
  for (int ct = 0; ct < 16; ++ct)
#pragma unroll
    for (int j = 0; j < 4; ++j) sm[j] += acc[ct][j];
#pragma unroll
  for (int j = 0; j < 4; ++j) {
    sm[j] += __shfl_xor(sm[j], 1, 16);
    sm[j] += __shfl_xor(sm[j], 2, 16);
    sm[j] += __shfl_xor(sm[j], 4, 16);
    sm[j] += __shfl_xor(sm[j], 8, 16);
    sm[j] *= (1.0f / 256.0f);          // mu
  }
  float vq[4] = {0.f, 0.f, 0.f, 0.f};
#pragma unroll
  for (int ct = 0; ct < 16; ++ct)
#pragma unroll
    for (int j = 0; j < 4; ++j) {
      float d = acc[ct][j] - sm[j];
      vq[j] += d * d;
    }
#pragma unroll
  for (int j = 0; j < 4; ++j) {
    vq[j] += __shfl_xor(vq[j], 1, 16);
    vq[j] += __shfl_xor(vq[j], 2, 16);
    vq[j] += __shfl_xor(vq[j], 4, 16);
    vq[j] += __shfl_xor(vq[j], 8, 16);
    vq[j] = rsqrtf(vq[j] * (1.0f / 256.0f) + 1e-5f);   // rs
  }
#pragma unroll
  for (int ct = 0; ct < 16; ++ct) {
    const int c = ct * 16 + lr;
    const float gc = gv[c], bc = bv[c];
#pragma unroll
    for (int j = 0; j < 4; ++j) {
      const int r = rows0 + w * 16 + lg * 4 + j;
      out[(size_t)r * DD + c] = (acc[ct][j] - sm[j]) * vq[j] * gc + bc;
    }
  }
}

// ---------------------------------------------------------------------------
// Swapped-QK^T 32x32x16 flash attention, v11 (K+V both double-buffered).
// 512 thr (8 waves), wave owns 32 q-rows, QBLK=256, KVBLK=64.
// ALL staging for tile t+1 issues at the top of tile t into the ^1 buffers;
// no mid-tile barriers; one __syncthreads per tile whose vmcnt drain waits
// on loads a full tile old (~free). Pre-swizzled layouts (K ^r&31, V ^d&7).
// ---------------------------------------------------------------------------
__global__ __launch_bounds__(512) void attn_partial_kernel(
    const _Float16* __restrict__ Q, const _Float16* __restrict__ K,
    const _Float16* __restrict__ VT, _Float16* __restrict__ Op,
    float* __restrict__ Mp, float* __restrict__ Lp, int nsplit)
{
  __shared__ _Float16 Ks[2][KVBLK * DD];   // 2 x 32 KB
  __shared__ _Float16 Vt[2][DD * KVBLK];   // 2 x 32 KB
  __shared__ float    Lw[8][32];           // 1 KB per-wave broadcast

  const int t     = threadIdx.x;
  const int lane  = t & 63;
  const int w     = t >> 6;
  const int lid   = blockIdx.x;
  const int b     = lid & 7;
  const int inner = lid >> 3;
  const int lsn   = (nsplit == 4) ? 2 : 1;
  const int split = inner & (nsplit - 1);
  const int q0    = (inner >> lsn) * QBLK;
  const int ntsp  = NTILES / nsplit;
  const int kt0   = split * ntsp;
  const int ql    = lane & 31;
  const int hi    = lane >> 5;

  f16x8 qf[16];
  {
    const _Float16* qrow = Q + ((size_t)b * SEQ + q0 + w * 32 + ql) * DD;
#pragma unroll
    for (int ks = 0; ks < 16; ++ks)
      qf[ks] = *(const f16x8*)(qrow + ks * 16 + hi * 8);
  }

  const char* Kb = (const char*)(K + (size_t)b * SEQ * DD);
  const char* Vb = (const char*)(VT + (size_t)b * NTILES * (DD * KVBLK));

  auto STAGE_K = [&](int ktAbs, int buf) {
    const char* kg = Kb + (size_t)ktAbs * (KVBLK * DD) * 2;
    char* kl = (char*)&Ks[buf][0];
#pragma unroll
    for (int i = 0; i < 4; ++i) {
      int off = i * 8192 + t * 16;
      __builtin_amdgcn_global_load_lds((const void*)(kg + off), (void*)(kl + off),
                                       16, 0, 0);
    }
  };
  auto STAGE_V = [&](int ktAbs, int buf) {
    const char* vg = Vb + (size_t)ktAbs * (DD * KVBLK) * 2;
    char* vl = (char*)&Vt[buf][0];
#pragma unroll
    for (int i = 0; i < 4; ++i) {
      int off = i * 8192 + t * 16;
      __builtin_amdgcn_global_load_lds((const void*)(vg + off), (void*)(vl + off),
                                       16, 0, 0);
    }
  };

  f32x16 cacc[8];
#pragma unroll
  for (int i = 0; i < 8; ++i)
#pragma unroll
    for (int r = 0; r < 16; ++r) cacc[i][r] = 0.f;
  float mrun = -1e30f, lrun = 0.f;

  STAGE_K(kt0, 0);
  STAGE_V(kt0, 0);
  __syncthreads();

  int cur = 0;
  for (int kt = 0; kt < ntsp; ++kt) {
    const bool pre = (kt + 1 < ntsp);
    if (pre) {                             // fire-and-forget, full tile to land
      STAGE_K(kt0 + kt + 1, cur ^ 1);
      STAGE_V(kt0 + kt + 1, cur ^ 1);
    }

    const char* KsC = (const char*)&Ks[cur][0];
    const char* VtC = (const char*)&Vt[cur][0];
    f16x8 pa0, pa1;

    // ================= S^T tile 0 (kv rows 0..31) =================
    f32x16 sc;
#pragma unroll
    for (int r = 0; r < 16; ++r) sc[r] = 0.f;
    __builtin_amdgcn_s_setprio(1);
#pragma unroll
    for (int ks = 0; ks < 16; ++ks) {
      f16x8 kf = *(const f16x8*)(KsC + (ql << 9) + (((ks * 2 + hi) ^ ql) << 4));
      sc = __builtin_amdgcn_mfma_f32_32x32x16_f16(kf, qf[ks], sc, 0, 0, 0);
    }
    __builtin_amdgcn_s_setprio(0);

    // ---- softmax tile 0 ----
    {
      float tm = sc[0];
#pragma unroll
      for (int r = 1; r < 16; ++r) tm = fmaxf(tm, sc[r]);
      tm = fmaxf(tm, __shfl_xor(tm, 32));
      if (__any(tm > mrun + 8.f)) {
        float mnew = fmaxf(mrun, tm);
        float scl  = __expf(mrun - mnew);
        if (lane < 32) Lw[w][lane] = scl;
#pragma unroll
        for (int r = 0; r < 16; ++r) {
          float s = Lw[w][(r & 3) + 8 * (r >> 2) + 4 * hi];
#pragma unroll
          for (int dt = 0; dt < 8; ++dt) cacc[dt][r] *= s;
        }
        lrun *= scl;
        mrun = mnew;
      }
      float ps = 0.f;
#pragma unroll
      for (int r = 0; r < 16; ++r) {
        float p = __expf(sc[r] - mrun);
        sc[r] = p; ps += p;
      }
      ps += __shfl_xor(ps, 32);
      lrun += ps;
#pragma unroll
      for (int h = 0; h < 2; ++h) {
        const int rb = h * 8;
        unsigned x1 = __builtin_bit_cast(unsigned,
            __builtin_amdgcn_cvt_pkrtz(sc[rb + 0], sc[rb + 1]));
        unsigned y1 = __builtin_bit_cast(unsigned,
            __builtin_amdgcn_cvt_pkrtz(sc[rb + 4], sc[rb + 5]));
        unsigned x2 = __builtin_bit_cast(unsigned,
            __builtin_amdgcn_cvt_pkrtz(sc[rb + 2], sc[rb + 3]));
        unsigned y2 = __builtin_bit_cast(unsigned,
            __builtin_amdgcn_cvt_pkrtz(sc[rb + 6], sc[rb + 7]));
        asm volatile("v_permlane32_swap_b32 %0, %1" : "+v"(x1), "+v"(y1));
        asm volatile("v_permlane32_swap_b32 %0, %1" : "+v"(x2), "+v"(y2));
        union { unsigned u[4]; f16x8 v; } pu;
        pu.u[0] = x1; pu.u[1] = x2; pu.u[2] = y1; pu.u[3] = y2;
        if (h == 0) pa0 = pu.v; else pa1 = pu.v;
      }
    }

    // ---- PV half 0 : st 0,1 (kv rows 0..31) ----
    __builtin_amdgcn_s_setprio(1);
#pragma unroll
    for (int dt = 0; dt < 8; ++dt) {
      const char* vrow = VtC + ((dt * 32 + ql) << 7);
      f16x8 v0 = *(const f16x8*)(vrow + (((0 * 2 + hi) ^ (ql & 7)) << 4));
      f16x8 v1 = *(const f16x8*)(vrow + (((1 * 2 + hi) ^ (ql & 7)) << 4));
      cacc[dt] = __builtin_amdgcn_mfma_f32_32x32x16_f16(pa0, v0, cacc[dt], 0, 0, 0);
      cacc[dt] = __builtin_amdgcn_mfma_f32_32x32x16_f16(pa1, v1, cacc[dt], 0, 0, 0);
    }
    __builtin_amdgcn_s_setprio(0);

    // ================= S^T tile 1 (kv rows 32..63) =================
#pragma unroll
    for (int r = 0; r < 16; ++r) sc[r] = 0.f;
    __builtin_amdgcn_s_setprio(1);
#pragma unroll
    for (int ks = 0; ks < 16; ++ks) {
      f16x8 kf = *(const f16x8*)(KsC + ((32 + ql) << 9) + (((ks * 2 + hi) ^ ql) << 4));
      sc = __builtin_amdgcn_mfma_f32_32x32x16_f16(kf, qf[ks], sc, 0, 0, 0);
    }
    __builtin_amdgcn_s_setprio(0);

    // ---- softmax tile 1 (rescale covers half-0 already in cacc) ----
    {
      float tm = sc[0];
#pragma unroll
      for (int r = 1; r < 16; ++r) tm = fmaxf(tm, sc[r]);
      tm = fmaxf(tm, __shfl_xor(tm, 32));
      if (__any(tm > mrun + 8.f)) {
        float mnew = fmaxf(mrun, tm);
        float scl  = __expf(mrun - mnew);
        if (lane < 32) Lw[w][lane] = scl;
#pragma unroll
        for (int r = 0; r < 16; ++r) {
          float s = Lw[w][(r & 3) + 8 * (r >> 2) + 4 * hi];
#pragma unroll
          for (int dt = 0; dt < 8; ++dt) cacc[dt][r] *= s;
        }
        lrun *= scl;
        mrun = mnew;
      }
      float ps = 0.f;
#pragma unroll
      for (int r = 0; r < 16; ++r) {
        float p = __expf(sc[r] - mrun);
        sc[r] = p; ps += p;
      }
      ps += __shfl_xor(ps, 32);
      lrun += ps;
#pragma unroll
      for (int h = 0; h < 2; ++h) {
        const int rb = h * 8;
        unsigned x1 = __builtin_bit_cast(unsigned,
            __builtin_amdgcn_cvt_pkrtz(sc[rb + 0], sc[rb + 1]));
        unsigned y1 = __builtin_bit_cast(unsigned,
            __builtin_amdgcn_cvt_pkrtz(sc[rb + 4], sc[rb + 5]));
        unsigned x2 = __builtin_bit_cast(unsigned,
            __builtin_amdgcn_cvt_pkrtz(sc[rb + 2], sc[rb + 3]));
        unsigned y2 = __builtin_bit_cast(unsigned,
            __builtin_amdgcn_cvt_pkrtz(sc[rb + 6], sc[rb + 7]));
        asm volatile("v_permlane32_swap_b32 %0, %1" : "+v"(x1), "+v"(y1));
        asm volatile("v_permlane32_swap_b32 %0, %1" : "+v"(x2), "+v"(y2));
        union { unsigned u[4]; f16x8 v; } pu;
        pu.u[0] = x1; pu.u[1] = x2; pu.u[2] = y1; pu.u[3] = y2;
        if (h == 0) pa0 = pu.v; else pa1 = pu.v;
      }
    }

    // ---- PV half 1 : st 2,3 (kv rows 32..63) ----
    __builtin_amdgcn_s_setprio(1);
#pragma unroll
    for (int dt = 0; dt < 8; ++dt) {
      const char* vrow = VtC + ((dt * 32 + ql) << 7);
      f16x8 v0 = *(const f16x8*)(vrow + (((2 * 2 + hi) ^ (ql & 7)) << 4));
      f16x8 v1 = *(const f16x8*)(vrow + (((3 * 2 + hi) ^ (ql & 7)) << 4));
      cacc[dt] = __builtin_amdgcn_mfma_f32_32x32x16_f16(pa0, v0, cacc[dt], 0, 0, 0);
      cacc[dt] = __builtin_amdgcn_mfma_f32_32x32x16_f16(pa1, v1, cacc[dt], 0, 0, 0);
    }
    __builtin_amdgcn_s_setprio(0);

    __syncthreads();   // vmcnt drain: K/V(t+1) issued a full tile ago (~free)
    cur ^= 1;
  }

  // ---- epilogue: NORMALIZED partial ctx (f16) + m/l -----------------------
  if (lane < 32) {
    const size_t R = (size_t)b * SEQ + q0 + w * 32 + lane;
    Mp[(size_t)split * RROWS + R] = mrun;
    Lp[(size_t)split * RROWS + R] = lrun;
    Lw[w][lane] = lrun;
  }
#pragma unroll
  for (int r = 0; r < 16; ++r) {
    const int q = (r & 3) + 8 * (r >> 2) + 4 * hi;
    const float inv = 1.0f / Lw[w][q];
    const size_t R = (size_t)b * SEQ + q0 + w * 32 + q;
#pragma unroll
    for (int dt = 0; dt < 8; ++dt)
      Op[((size_t)split * RROWS + R) * DD + dt * 32 + ql] =
          (_Float16)(cacc[dt][r] * inv);
  }
}

// ---------------------------------------------------------------------------
extern "C" void kernel_launch(void* const* d_in, const int* in_sizes, int n_in,
                              void* d_out, int out_size, void* d_ws, size_t ws_size,
                              hipStream_t stream) {
  const float* x  = (const float*)d_in[0];
  const float* Wq = (const float*)d_in[1];
  const float* bq = (const float*)d_in[2];
  const float* Wk = (const float*)d_in[3];
  const float* bk = (const float*)d_in[4];
  const float* Wv = (const float*)d_in[5];
  const float* bv = (const float*)d_in[6];
  const float* Wd = (const float*)d_in[7];
  const float* bd = (const float*)d_in[8];
  const float* g  = (const float*)d_in[9];
  const float* b  = (const float*)d_in[10];
  float* out = (float*)d_out;

  const int nsplit = (ws_size >= (58ull << 20)) ? 4 : 2;

  char* W = (char*)d_ws;
  _Float16* Qh   = (_Float16*)(W + (0ull  << 20));   //  8 MB
  _Float16* Kh   = (_Float16*)(W + (8ull  << 20));   //  8 MB, swizzled ^r&31
  _Float16* VtG  = (_Float16*)(W + (16ull << 20));   //  8 MB, tiled+swizzled
  _Float16* Op   = (_Float16*)(W + (24ull << 20));   //  8*nsplit MB
  size_t tail = (24ull << 20) + (size_t)nsplit * (8ull << 20);
  float*    Mp   = (float*)(W + tail);
  float*    Lp   = Mp + (size_t)nsplit * RROWS;
  _Float16* Wh   = (_Float16*)(Lp + (size_t)nsplit * RROWS);   // 512 KB

  cast_w_kernel<<<dim3(32, 4), 256, 0, stream>>>(Wq, Wk, Wv, Wd, Wh);

  dim3 gg(RROWS / 64, DD / 128);   // (256, 2)
  gemm_qkv_kernel<<<gg, 256, 0, stream>>>(x, Wh, bq, bk, bv, Qh, Kh, VtG);

  // grid: 8 q-tiles x nsplit x 8 batches (= 256 blocks at nsplit=4)
  attn_partial_kernel<<<dim3((SEQ / QBLK) * nsplit * NB), 512, 0, stream>>>(
      Qh, Kh, VtG, Op, Mp, Lp, nsplit);

  // combine + out-proj + residual + LN fused; 256 blocks of 64 full rows
  gemm_outln_kernel<<<dim3(RROWS / 64), 256, 0, stream>>>(
      Op, Mp, Lp, nsplit, Wh + 3 * 65536, bd, x, g, b, out);
}

// Round 25
// 92.867 us; speedup vs baseline: 1.1422x; 1.1422x over previous
//
#include <hip/hip_runtime.h>
#include <hip/hip_bf16.h>
#include <hip/hip_fp16.h>
#include <cstdint>

// B=8, S=2048, D=256 fused attention block, fp32 in/out.
// Round 25: revert to the round-23 configuration (best measured: 93.1us,
// 12.1x over baseline). Round 24's K-double-buffer + barrier removal
// regressed (regalloc pushed past 128 VGPR -> spill returned, attn 55->70us);
// the round-22/23 barrier structure is load-bearing for the allocation.
// Final structure:
//   cast_w -> gemm_qkv (fused Q/K/V proj, pre-swizzled K ^r&31, V tiled ^d&7)
//   attn_partial: swapped-QK^T 32x32x16, 8-wave QBLK=256, K single-buffered
//     + raw mid-tile barrier, V double-buffered, half-PV interleave,
//     defer-max softmax, cvt_pkrtz+permlane32_swap P-pack, nsplit=4 split-K
//   gemm_outln: combine + out-proj + residual + LayerNorm fused.

#define RROWS 16384
#define DD 256
#define SEQ 2048
#define NB 8
#define QBLK 256
#define KVBLK 64
#define NTILES (SEQ / KVBLK)

typedef _Float16 f16x8 __attribute__((ext_vector_type(8)));
typedef _Float16 f16x4 __attribute__((ext_vector_type(4)));
typedef float f32x4 __attribute__((ext_vector_type(4)));
typedef float f32x16 __attribute__((ext_vector_type(16)));

// ---------------------------------------------------------------------------
// weight cast (q,k,v,d -> Wh[4][65536])
// ---------------------------------------------------------------------------
__global__ __launch_bounds__(256) void cast_w_kernel(
    const float* __restrict__ w0, const float* __restrict__ w1,
    const float* __restrict__ w2, const float* __restrict__ w3,
    _Float16* __restrict__ dst)
{
  const float* srcs[4] = {w0, w1, w2, w3};
  const float* src = srcs[blockIdx.y];
  _Float16* d = dst + (size_t)blockIdx.y * 65536;
  const size_t i = ((size_t)blockIdx.x * 256 + threadIdx.x) * 8;
  float4 a = *(const float4*)&src[i];
  float4 b = *(const float4*)&src[i + 4];
  f16x8 h = { (_Float16)a.x, (_Float16)a.y, (_Float16)a.z, (_Float16)a.w,
              (_Float16)b.x, (_Float16)b.y, (_Float16)b.z, (_Float16)b.w };
  *(f16x8*)&d[i] = h;
}

// ---------------------------------------------------------------------------
// Fused QKV projection: X fp32 -> {Qh (row-major), Kh (swizzled ^r&31),
// VtG (tiled [b][s/64][256 d][64 s], granule-swizzled ^d&7)}.
// ---------------------------------------------------------------------------
__global__ __launch_bounds__(256) void gemm_qkv_kernel(
    const float* __restrict__ X, const _Float16* __restrict__ Wh,
    const float* __restrict__ bq, const float* __restrict__ bk,
    const float* __restrict__ bv,
    _Float16* __restrict__ Qh, _Float16* __restrict__ Kh,
    _Float16* __restrict__ VtG)
{
  __shared__ _Float16 smem[128 * 264];
  const int t     = threadIdx.x;
  const int lane  = t & 63;
  const int w     = t >> 6;
  const int rows0 = blockIdx.x * 64;
  const int col0  = blockIdx.y * 128;
  const int lr = lane & 15;
  const int lg = lane >> 4;

  f16x8 qf[8];
  {
    const float* xrow = X + (size_t)(rows0 + w * 16 + lr) * DD;
#pragma unroll
    for (int ks = 0; ks < 8; ++ks) {
      float4 a = *(const float4*)&xrow[ks * 32 + lg * 8];
      float4 b = *(const float4*)&xrow[ks * 32 + lg * 8 + 4];
      qf[ks] = (f16x8){ (_Float16)a.x, (_Float16)a.y, (_Float16)a.z, (_Float16)a.w,
                        (_Float16)b.x, (_Float16)b.y, (_Float16)b.z, (_Float16)b.w };
    }
  }

  for (int o = 0; o < 3; ++o) {
    const _Float16* W = Wh + (size_t)o * 65536;
    __syncthreads();
#pragma unroll
    for (int i = 0; i < 16; ++i) {
      int ch = i * 256 + t;
      int er = ch >> 5, kc = (ch & 31) * 8;
      *(f16x8*)&smem[er * 264 + kc] = *(const f16x8*)&W[(size_t)(col0 + er) * DD + kc];
    }
    __syncthreads();

    f32x4 acc[8];
#pragma unroll
    for (int i = 0; i < 8; ++i) acc[i] = (f32x4){0.f, 0.f, 0.f, 0.f};
#pragma unroll
    for (int ct = 0; ct < 8; ++ct)
#pragma unroll
      for (int ks = 0; ks < 8; ++ks) {
        f16x8 wf = *(const f16x8*)&smem[(ct * 16 + lr) * 264 + ks * 32 + lg * 8];
        acc[ct] = __builtin_amdgcn_mfma_f32_16x16x32_f16(qf[ks], wf, acc[ct], 0, 0, 0);
      }

    const float* bp = (o == 0) ? bq : (o == 1) ? bk : bv;
    float bf[8];
#pragma unroll
    for (int ct = 0; ct < 8; ++ct) bf[ct] = bp[col0 + ct * 16 + lr];

    if (o == 0) {
#pragma unroll
      for (int ct = 0; ct < 8; ++ct)
#pragma unroll
        for (int j = 0; j < 4; ++j) {
          int r = rows0 + w * 16 + lg * 4 + j;
          Qh[(size_t)r * DD + col0 + ct * 16 + lr] = (_Float16)(acc[ct][j] + bf[ct]);
        }
    } else if (o == 1) {
#pragma unroll
      for (int ct = 0; ct < 8; ++ct)
#pragma unroll
        for (int j = 0; j < 4; ++j) {
          int r = rows0 + w * 16 + lg * 4 + j;
          int c = col0 + ct * 16 + lr;
          Kh[(size_t)r * DD + (((c >> 3) ^ (r & 31)) << 3) + (c & 7)] =
              (_Float16)(acc[ct][j] + bf[ct]);
        }
    } else {
      __syncthreads();
      _Float16* T = smem;   // [128 e][72 s]
#pragma unroll
      for (int ct = 0; ct < 8; ++ct)
#pragma unroll
        for (int j = 0; j < 4; ++j)
          T[(ct * 16 + lr) * 72 + (w * 16 + lg * 4 + j)] = (_Float16)(acc[ct][j] + bf[ct]);
      __syncthreads();
      const int bIdx = rows0 >> 11;
      const int tIdx = (rows0 & (SEQ - 1)) >> 6;
      _Float16* base = VtG + (((size_t)bIdx * NTILES + tIdx) * DD + col0) * KVBLK;
#pragma unroll
      for (int p = 0; p < 4; ++p) {
        int ch = p * 256 + t;
        int e = ch >> 3, sc = (ch & 7) * 8;
        int g = (sc >> 3) ^ (e & 7);
        *(f16x8*)&base[(size_t)e * KVBLK + (g << 3)] = *(const f16x8*)&T[e * 72 + sc];
      }
    }
  }
}

// ---------------------------------------------------------------------------
// (combine + out-projection + residual + LayerNorm) fused.
// ---------------------------------------------------------------------------
__global__ __launch_bounds__(256) void gemm_outln_kernel(
    const _Float16* __restrict__ Op, const float* __restrict__ Mp,
    const float* __restrict__ Lp, int nsplit,
    const _Float16* __restrict__ W, const float* __restrict__ bias,
    const float* __restrict__ res, const float* __restrict__ gv,
    const float* __restrict__ bv, float* __restrict__ out)
{
  __shared__ _Float16 smem[128 * 264];
  const int t     = threadIdx.x;
  const int lane  = t & 63;
  const int w     = t >> 6;
  const int rows0 = blockIdx.x * 64;
  const int lr = lane & 15;
  const int lg = lane >> 4;
  const size_t R = (size_t)rows0 + w * 16 + lr;     // this thread's ctx row

  // combine weights for row R
  float wgt[4];
  {
    float ms = -1e30f;
    for (int s = 0; s < nsplit; ++s) ms = fmaxf(ms, Mp[(size_t)s * RROWS + R]);
    float ctot = 0.f;
    for (int s = 0; s < nsplit; ++s) {
      float c = __expf(Mp[(size_t)s * RROWS + R] - ms) * Lp[(size_t)s * RROWS + R];
      wgt[s] = c; ctot += c;
    }
    float inv = 1.0f / ctot;
    for (int s = 0; s < nsplit; ++s) wgt[s] *= inv;
  }

  // A fragments = sum_s wgt[s] * Op_s[row R]
  f16x8 qf[8];
#pragma unroll
  for (int ks = 0; ks < 8; ++ks) {
    float cf[8] = {0.f, 0.f, 0.f, 0.f, 0.f, 0.f, 0.f, 0.f};
    for (int s = 0; s < nsplit; ++s) {
      f16x8 o = *(const f16x8*)&Op[((size_t)s * RROWS + R) * DD + ks * 32 + lg * 8];
#pragma unroll
      for (int e = 0; e < 8; ++e) cf[e] += wgt[s] * (float)o[e];
    }
    qf[ks] = (f16x8){ (_Float16)cf[0], (_Float16)cf[1], (_Float16)cf[2], (_Float16)cf[3],
                      (_Float16)cf[4], (_Float16)cf[5], (_Float16)cf[6], (_Float16)cf[7] };
  }

  f32x4 acc[16];
#pragma unroll
  for (int i = 0; i < 16; ++i) acc[i] = (f32x4){0.f, 0.f, 0.f, 0.f};

  for (int half = 0; half < 2; ++half) {
    const int col0 = half * 128;
    __syncthreads();
#pragma unroll
    for (int i = 0; i < 16; ++i) {
      int ch = i * 256 + t;
      int er = ch >> 5, kc = (ch & 31) * 8;
      *(f16x8*)&smem[er * 264 + kc] = *(const f16x8*)&W[(size_t)(col0 + er) * DD + kc];
    }
    __syncthreads();
#pragma unroll
    for (int ct = 0; ct < 8; ++ct)
#pragma unroll
      for (int ks = 0; ks < 8; ++ks) {
        f16x8 wf = *(const f16x8*)&smem[(ct * 16 + lr) * 264 + ks * 32 + lg * 8];
        acc[half * 8 + ct] =
            __builtin_amdgcn_mfma_f32_16x16x32_f16(qf[ks], wf, acc[half * 8 + ct], 0, 0, 0);
      }
  }

  // h = acc + bias + x
#pragma unroll
  for (int ct = 0; ct < 16; ++ct) {
    const int c = ct * 16 + lr;
    const float bf = bias[c];
#pragma unroll
    for (int j = 0; j < 4; ++j) {
      const int r = rows0 + w * 16 + lg * 4 + j;
      acc[ct][j] += bf + res[(size_t)r * DD + c];
    }
  }

  // LN over 256 cols (16 lr-lanes x 16 cts per lg group)
  float sm[4] = {0.f, 0.f, 0.f, 0.f};
#pragma unroll
  for (int ct = 0; ct < 16; ++ct)
#pragma unroll
    for (int j = 0; j < 4; ++j) sm[j] += acc[ct][j];
#pragma unroll
  for (int j = 0; j < 4; ++j) {
    sm[j] += __shfl_xor(sm[j], 1, 16);
    sm[j] += __shfl_xor(sm[j], 2, 16);
    sm[j] += __shfl_xor(sm[j], 4, 16);
    sm[j] += __shfl_xor(sm[j], 8, 16);
    sm[j] *= (1.0f / 256.0f);          // mu
  }
  float vq[4] = {0.f, 0.f, 0.f, 0.f};
#pragma unroll
  for (int ct = 0; ct < 16; ++ct)
#pragma unroll
    for (int j = 0; j < 4; ++j) {
      float d = acc[ct][j] - sm[j];
      vq[j] += d * d;
    }
#pragma unroll
  for (int j = 0; j < 4; ++j) {
    vq[j] += __shfl_xor(vq[j], 1, 16);
    vq[j] += __shfl_xor(vq[j], 2, 16);
    vq[j] += __shfl_xor(vq[j], 4, 16);
    vq[j] += __shfl_xor(vq[j], 8, 16);
    vq[j] = rsqrtf(vq[j] * (1.0f / 256.0f) + 1e-5f);   // rs
  }
#pragma unroll
  for (int ct = 0; ct < 16; ++ct) {
    const int c = ct * 16 + lr;
    const float gc = gv[c], bc = bv[c];
#pragma unroll
    for (int j = 0; j < 4; ++j) {
      const int r = rows0 + w * 16 + lg * 4 + j;
      out[(size_t)r * DD + c] = (acc[ct][j] - sm[j]) * vq[j] * gc + bc;
    }
  }
}

// ---------------------------------------------------------------------------
// Swapped-QK^T 32x32x16 flash attention (round-22/23 kernel, verbatim).
// 512 thr (8 waves), wave owns 32 q-rows, QBLK=256, KVBLK=64.
// Per tile: QK0 -> SM0+pack -> PV(st0,1) -> QK1 -> rawbar+STAGE_K ->
// SM1+pack -> PV(st2,3) -> drain. K single, V dbuf, pre-swizzled layouts.
// ---------------------------------------------------------------------------
__global__ __launch_bounds__(512) void attn_partial_kernel(
    const _Float16* __restrict__ Q, const _Float16* __restrict__ K,
    const _Float16* __restrict__ VT, _Float16* __restrict__ Op,
    float* __restrict__ Mp, float* __restrict__ Lp, int nsplit)
{
  __shared__ _Float16 Ks[KVBLK * DD];      // 32 KB single
  __shared__ _Float16 Vt[2][DD * KVBLK];   // 2 x 32 KB
  __shared__ float    Lw[8][32];           // 1 KB per-wave broadcast

  const int t     = threadIdx.x;
  const int lane  = t & 63;
  const int w     = t >> 6;
  const int lid   = blockIdx.x;
  const int b     = lid & 7;
  const int inner = lid >> 3;
  const int lsn   = (nsplit == 4) ? 2 : 1;
  const int split = inner & (nsplit - 1);
  const int q0    = (inner >> lsn) * QBLK;
  const int ntsp  = NTILES / nsplit;
  const int kt0   = split * ntsp;
  const int ql    = lane & 31;
  const int hi    = lane >> 5;

  f16x8 qf[16];
  {
    const _Float16* qrow = Q + ((size_t)b * SEQ + q0 + w * 32 + ql) * DD;
#pragma unroll
    for (int ks = 0; ks < 16; ++ks)
      qf[ks] = *(const f16x8*)(qrow + ks * 16 + hi * 8);
  }

  const char* Kb = (const char*)(K + (size_t)b * SEQ * DD);
  const char* Vb = (const char*)(VT + (size_t)b * NTILES * (DD * KVBLK));

  auto STAGE_K = [&](int ktAbs) {
    const char* kg = Kb + (size_t)ktAbs * (KVBLK * DD) * 2;
    char* kl = (char*)&Ks[0];
#pragma unroll
    for (int i = 0; i < 4; ++i) {
      int off = i * 8192 + t * 16;
      __builtin_amdgcn_global_load_lds((const void*)(kg + off), (void*)(kl + off),
                                       16, 0, 0);
    }
  };
  auto STAGE_V = [&](int ktAbs, int buf) {
    const char* vg = Vb + (size_t)ktAbs * (DD * KVBLK) * 2;
    char* vl = (char*)&Vt[buf][0];
#pragma unroll
    for (int i = 0; i < 4; ++i) {
      int off = i * 8192 + t * 16;
      __builtin_amdgcn_global_load_lds((const void*)(vg + off), (void*)(vl + off),
                                       16, 0, 0);
    }
  };

  f32x16 cacc[8];
#pragma unroll
  for (int i = 0; i < 8; ++i)
#pragma unroll
    for (int r = 0; r < 16; ++r) cacc[i][r] = 0.f;
  float mrun = -1e30f, lrun = 0.f;

  STAGE_V(kt0, 0);
  STAGE_K(kt0);
  __syncthreads();

  int cur = 0;
  for (int kt = 0; kt < ntsp; ++kt) {
    const bool pre = (kt + 1 < ntsp);
    if (pre) STAGE_V(kt0 + kt + 1, cur ^ 1);

    const char* KsC = (const char*)&Ks[0];
    const char* VtC = (const char*)&Vt[cur][0];
    f16x8 pa0, pa1;

    // ================= S^T tile 0 (kv rows 0..31) =================
    f32x16 sc;
#pragma unroll
    for (int r = 0; r < 16; ++r) sc[r] = 0.f;
    __builtin_amdgcn_s_setprio(1);
#pragma unroll
    for (int ks = 0; ks < 16; ++ks) {
      f16x8 kf = *(const f16x8*)(KsC + (ql << 9) + (((ks * 2 + hi) ^ ql) << 4));
      sc = __builtin_amdgcn_mfma_f32_32x32x16_f16(kf, qf[ks], sc, 0, 0, 0);
    }
    __builtin_amdgcn_s_setprio(0);

    // ---- softmax tile 0 ----
    {
      float tm = sc[0];
#pragma unroll
      for (int r = 1; r < 16; ++r) tm = fmaxf(tm, sc[r]);
      tm = fmaxf(tm, __shfl_xor(tm, 32));
      if (__any(tm > mrun + 8.f)) {
        float mnew = fmaxf(mrun, tm);
        float scl  = __expf(mrun - mnew);
        if (lane < 32) Lw[w][lane] = scl;
#pragma unroll
        for (int r = 0; r < 16; ++r) {
          float s = Lw[w][(r & 3) + 8 * (r >> 2) + 4 * hi];
#pragma unroll
          for (int dt = 0; dt < 8; ++dt) cacc[dt][r] *= s;
        }
        lrun *= scl;
        mrun = mnew;
      }
      float ps = 0.f;
#pragma unroll
      for (int r = 0; r < 16; ++r) {
        float p = __expf(sc[r] - mrun);
        sc[r] = p; ps += p;
      }
      ps += __shfl_xor(ps, 32);
      lrun += ps;
#pragma unroll
      for (int h = 0; h < 2; ++h) {
        const int rb = h * 8;
        unsigned x1 = __builtin_bit_cast(unsigned,
            __builtin_amdgcn_cvt_pkrtz(sc[rb + 0], sc[rb + 1]));
        unsigned y1 = __builtin_bit_cast(unsigned,
            __builtin_amdgcn_cvt_pkrtz(sc[rb + 4], sc[rb + 5]));
        unsigned x2 = __builtin_bit_cast(unsigned,
            __builtin_amdgcn_cvt_pkrtz(sc[rb + 2], sc[rb + 3]));
        unsigned y2 = __builtin_bit_cast(unsigned,
            __builtin_amdgcn_cvt_pkrtz(sc[rb + 6], sc[rb + 7]));
        asm volatile("v_permlane32_swap_b32 %0, %1" : "+v"(x1), "+v"(y1));
        asm volatile("v_permlane32_swap_b32 %0, %1" : "+v"(x2), "+v"(y2));
        union { unsigned u[4]; f16x8 v; } pu;
        pu.u[0] = x1; pu.u[1] = x2; pu.u[2] = y1; pu.u[3] = y2;
        if (h == 0) pa0 = pu.v; else pa1 = pu.v;
      }
    }

    // ---- PV half 0 : st 0,1 (kv rows 0..31) ----
    __builtin_amdgcn_s_setprio(1);
#pragma unroll
    for (int dt = 0; dt < 8; ++dt) {
      const char* vrow = VtC + ((dt * 32 + ql) << 7);
      f16x8 v0 = *(const f16x8*)(vrow + (((0 * 2 + hi) ^ (ql & 7)) << 4));
      f16x8 v1 = *(const f16x8*)(vrow + (((1 * 2 + hi) ^ (ql & 7)) << 4));
      cacc[dt] = __builtin_amdgcn_mfma_f32_32x32x16_f16(pa0, v0, cacc[dt], 0, 0, 0);
      cacc[dt] = __builtin_amdgcn_mfma_f32_32x32x16_f16(pa1, v1, cacc[dt], 0, 0, 0);
    }
    __builtin_amdgcn_s_setprio(0);

    // ================= S^T tile 1 (kv rows 32..63) =================
#pragma unroll
    for (int r = 0; r < 16; ++r) sc[r] = 0.f;
    __builtin_amdgcn_s_setprio(1);
#pragma unroll
    for (int ks = 0; ks < 16; ++ks) {
      f16x8 kf = *(const f16x8*)(KsC + ((32 + ql) << 9) + (((ks * 2 + hi) ^ ql) << 4));
      sc = __builtin_amdgcn_mfma_f32_32x32x16_f16(kf, qf[ks], sc, 0, 0, 0);
    }
    __builtin_amdgcn_s_setprio(0);

    // all K reads of this tile consumed -> safe to restage Ks
    __builtin_amdgcn_s_barrier();
    if (pre) STAGE_K(kt0 + kt + 1);      // lands during softmax + PV

    // ---- softmax tile 1 (rescale covers half-0 already in cacc) ----
    {
      float tm = sc[0];
#pragma unroll
      for (int r = 1; r < 16; ++r) tm = fmaxf(tm, sc[r]);
      tm = fmaxf(tm, __shfl_xor(tm, 32));
      if (__any(tm > mrun + 8.f)) {
        float mnew = fmaxf(mrun, tm);
        float scl  = __expf(mrun - mnew);
        if (lane < 32) Lw[w][lane] = scl;
#pragma unroll
        for (int r = 0; r < 16; ++r) {
          float s = Lw[w][(r & 3) + 8 * (r >> 2) + 4 * hi];
#pragma unroll
          for (int dt = 0; dt < 8; ++dt) cacc[dt][r] *= s;
        }
        lrun *= scl;
        mrun = mnew;
      }
      float ps = 0.f;
#pragma unroll
      for (int r = 0; r < 16; ++r) {
        float p = __expf(sc[r] - mrun);
        sc[r] = p; ps += p;
      }
      ps += __shfl_xor(ps, 32);
      lrun += ps;
#pragma unroll
      for (int h = 0; h < 2; ++h) {
        const int rb = h * 8;
        unsigned x1 = __builtin_bit_cast(unsigned,
            __builtin_amdgcn_cvt_pkrtz(sc[rb + 0], sc[rb + 1]));
        unsigned y1 = __builtin_bit_cast(unsigned,
            __builtin_amdgcn_cvt_pkrtz(sc[rb + 4], sc[rb + 5]));
        unsigned x2 = __builtin_bit_cast(unsigned,
            __builtin_amdgcn_cvt_pkrtz(sc[rb + 2], sc[rb + 3]));
        unsigned y2 = __builtin_bit_cast(unsigned,
            __builtin_amdgcn_cvt_pkrtz(sc[rb + 6], sc[rb + 7]));
        asm volatile("v_permlane32_swap_b32 %0, %1" : "+v"(x1), "+v"(y1));
        asm volatile("v_permlane32_swap_b32 %0, %1" : "+v"(x2), "+v"(y2));
        union { unsigned u[4]; f16x8 v; } pu;
        pu.u[0] = x1; pu.u[1] = x2; pu.u[2] = y1; pu.u[3] = y2;
        if (h == 0) pa0 = pu.v; else pa1 = pu.v;
      }
    }

    // ---- PV half 1 : st 2,3 (kv rows 32..63) ----
    __builtin_amdgcn_s_setprio(1);
#pragma unroll
    for (int dt = 0; dt < 8; ++dt) {
      const char* vrow = VtC + ((dt * 32 + ql) << 7);
      f16x8 v0 = *(const f16x8*)(vrow + (((2 * 2 + hi) ^ (ql & 7)) << 4));
      f16x8 v1 = *(const f16x8*)(vrow + (((3 * 2 + hi) ^ (ql & 7)) << 4));
      cacc[dt] = __builtin_amdgcn_mfma_f32_32x32x16_f16(pa0, v0, cacc[dt], 0, 0, 0);
      cacc[dt] = __builtin_amdgcn_mfma_f32_32x32x16_f16(pa1, v1, cacc[dt], 0, 0, 0);
    }
    __builtin_amdgcn_s_setprio(0);

    __syncthreads();   // drains vmcnt: K(t+1) + V(t+1) landed
    cur ^= 1;
  }

  // ---- epilogue: NORMALIZED partial ctx (f16) + m/l -----------------------
  if (lane < 32) {
    const size_t R = (size_t)b * SEQ + q0 + w * 32 + lane;
    Mp[(size_t)split * RROWS + R] = mrun;
    Lp[(size_t)split * RROWS + R] = lrun;
    Lw[w][lane] = lrun;
  }
#pragma unroll
  for (int r = 0; r < 16; ++r) {
    const int q = (r & 3) + 8 * (r >> 2) + 4 * hi;
    const float inv = 1.0f / Lw[w][q];
    const size_t R = (size_t)b * SEQ + q0 + w * 32 + q;
#pragma unroll
    for (int dt = 0; dt < 8; ++dt)
      Op[((size_t)split * RROWS + R) * DD + dt * 32 + ql] =
          (_Float16)(cacc[dt][r] * inv);
  }
}

// ---------------------------------------------------------------------------
extern "C" void kernel_launch(void* const* d_in, const int* in_sizes, int n_in,
                              void* d_out, int out_size, void* d_ws, size_t ws_size,
                              hipStream_t stream) {
  const float* x  = (const float*)d_in[0];
  const float* Wq = (const float*)d_in[1];
  const float* bq = (const float*)d_in[2];
  const float* Wk = (const float*)d_in[3];
  const float* bk = (const float*)d_in[4];
  const float* Wv = (const float*)d_in[5];
  const float* bv = (const float*)d_in[6];
  const float* Wd = (const float*)d_in[7];
  const float* bd = (const float*)d_in[8];
  const float* g  = (const float*)d_in[9];
  const float* b  = (const float*)d_in[10];
  float* out = (float*)d_out;

  const int nsplit = (ws_size >= (58ull << 20)) ? 4 : 2;

  char* W = (char*)d_ws;
  _Float16* Qh   = (_Float16*)(W + (0ull  << 20));   //  8 MB
  _Float16* Kh   = (_Float16*)(W + (8ull  << 20));   //  8 MB, swizzled ^r&31
  _Float16* VtG  = (_Float16*)(W + (16ull << 20));   //  8 MB, tiled+swizzled
  _Float16* Op   = (_Float16*)(W + (24ull << 20));   //  8*nsplit MB
  size_t tail = (24ull << 20) + (size_t)nsplit * (8ull << 20);
  float*    Mp   = (float*)(W + tail);
  float*    Lp   = Mp + (size_t)nsplit * RROWS;
  _Float16* Wh   = (_Float16*)(Lp + (size_t)nsplit * RROWS);   // 512 KB

  cast_w_kernel<<<dim3(32, 4), 256, 0, stream>>>(Wq, Wk, Wv, Wd, Wh);

  dim3 gg(RROWS / 64, DD / 128);   // (256, 2)
  gemm_qkv_kernel<<<gg, 256, 0, stream>>>(x, Wh, bq, bk, bv, Qh, Kh, VtG);

  // grid: 8 q-tiles x nsplit x 8 batches (= 256 blocks at nsplit=4)
  attn_partial_kernel<<<dim3((SEQ / QBLK) * nsplit * NB), 512, 0, stream>>>(
      Qh, Kh, VtG, Op, Mp, Lp, nsplit);

  // combine + out-proj + residual + LN fused; 256 blocks of 64 full rows
  gemm_outln_kernel<<<dim3(RROWS / 64), 256, 0, stream>>>(
      Op, Mp, Lp, nsplit, Wh + 3 * 65536, bd, x, g, b, out);
}